// Round 1
// baseline (222.109 us; speedup 1.0000x reference)
//
#include <hip/hip_runtime.h>

// BezierSurfaceFitter, single fused kernel.
// out[bc,i,j] = sum_p Bu[i,p]*T[bc,p,j];  T[bc,p,j] = sum_q K[bc,p,q]*Bv[j,q]
// H=W=256, M=N=31  =>  Bu == Bv == one 256x32 Bernstein table, computed
// per-thread (row tid) via the exact-in-fp64 recurrence
//   b_0 = (1-t)^31,  b_{k+1} = b_k * ((31-k)/(k+1)) * t/(1-t)
// (ratios constant-folded; differs from the direct formula by ~1e-14 rel,
// invisible under the ~1.5e-5 bf16 hi/lo split error).
//
// Phase 1: T row per thread in fp32 VALU (K row-major, wave-uniform s_load).
// Phase 2: D = T^T * Bu^T via mfma_f32_16x16x32_bf16, hi/lo 3-product fp32
// emulation. A-frags (T^T rows) and B-frags (Bu rows) both live in LDS with
// chunk index XOR-swizzled by (row>>1)&3 => full 32-bank coverage (validated
// pattern from the previous session's T-table).
// D[row=q*4+r][col=m]: 4 consecutive j at fixed i per lane => float4 store;
// wave store = 16 rows x 64 B, lines fully covered across the a-loop.

#define DEG 31

typedef short bf16x8 __attribute__((ext_vector_type(8)));  // 8 bf16 in 4 VGPRs
typedef float f32x4  __attribute__((ext_vector_type(4)));

__device__ __forceinline__ unsigned short f2bf_rne(float x) {
    unsigned int u = __float_as_uint(x);
    unsigned int r = (u + 0x7FFFu + ((u >> 16) & 1u)) >> 16;
    return (unsigned short)r;
}
__device__ __forceinline__ float bf2f(unsigned short h) {
    return __uint_as_float(((unsigned int)h) << 16);
}

__global__ __launch_bounds__(256) void bez_fused_kernel(
        const float* __restrict__ K,       // (768,32,32) fp32
        float* __restrict__ out) {         // (768,256,256) fp32
    // T^T rows (A-frags) and Bu rows (B-frags), hi/lo bf16. Row r: 32 bf16
    // (64 B); chunk c (8 bf16, 16 B) stored at swizzled slot c ^ ((r>>1)&3).
    __shared__ __align__(16) unsigned short sThi[256 * 32];  // 16 KB
    __shared__ __align__(16) unsigned short sTlo[256 * 32];  // 16 KB
    __shared__ __align__(16) unsigned short sBhi[256 * 32];  // 16 KB
    __shared__ __align__(16) unsigned short sBlo[256 * 32];  // 16 KB

    const int bc   = blockIdx.x;        // 0..767
    const int tid  = threadIdx.x;       // basis/T row index in phases 0-1
    const int lane = tid & 63;
    const int w    = tid >> 6;          // wave 0..3
    const int jsw  = (tid >> 1) & 3;

    // ---- phase 0: Bernstein row `tid` via fp64 recurrence ------------------
    double t   = ((double)tid + 0.5) * (1.0 / 256.0);   // exact
    double omt = 1.0 - t;                               // exact
    double r   = t / omt;
    double o2 = omt * omt, o4 = o2 * o2, o8 = o4 * o4, o16 = o8 * o8;
    double b  = o16 * o8 * o4 * o2 * omt;               // omt^31
    float breg[32];
    #pragma unroll
    for (int k = 0; k < 32; ++k) {
        breg[k] = (float)b;
        b *= ((double)(DEG - k) / (double)(k + 1)) * r; // ratio const-folded
    }
    // hi/lo split -> LDS B-table (B-frag layout, swizzled, same as T-table)
    #pragma unroll
    for (int c = 0; c < 4; ++c) {
        bf16x8 vh, vl;
        #pragma unroll
        for (int e = 0; e < 8; ++e) {
            float x = breg[c * 8 + e];
            unsigned short h = f2bf_rne(x);
            vh[e] = (short)h;
            vl[e] = (short)f2bf_rne(x - bf2f(h));
        }
        int off = tid * 32 + (c ^ jsw) * 8;
        *(bf16x8*)&sBhi[off] = vh;
        *(bf16x8*)&sBlo[off] = vl;
    }

    // ---- phase 1: T[p][tid] = sum_q K[bc,p,q] * breg[q] (fp32 VALU) --------
    const float* Kbc = K + (size_t)bc * 1024;   // wave-uniform -> s_load
    float treg[32];
    #pragma unroll
    for (int p = 0; p < 32; ++p) {
        float acc = 0.0f;
        #pragma unroll
        for (int qi = 0; qi < 32; ++qi)
            acc += Kbc[p * 32 + qi] * breg[qi];
        treg[p] = acc;
    }
    #pragma unroll
    for (int c = 0; c < 4; ++c) {
        bf16x8 vh, vl;
        #pragma unroll
        for (int e = 0; e < 8; ++e) {
            float x = treg[c * 8 + e];
            unsigned short h = f2bf_rne(x);
            vh[e] = (short)h;
            vl[e] = (short)f2bf_rne(x - bf2f(h));
        }
        int off = tid * 32 + (c ^ jsw) * 8;
        *(bf16x8*)&sThi[off] = vh;
        *(bf16x8*)&sTlo[off] = vl;
    }
    __syncthreads();

    // ---- phase 2: D = T^T * Bu^T, tiles 16x16, K=32 (one MFMA k-step) ------
    const int m = lane & 15;     // i within column-tile / A row j within tile
    const int q = lane >> 4;     // k-chunk for A/B; row-quad for D

    // A-frags: T^T rows for this wave's 4 j-tiles (jt = 4w+a), from LDS.
    bf16x8 Th[4], Tl[4];
    #pragma unroll
    for (int a = 0; a < 4; ++a) {
        int j = (w * 4 + a) * 16 + m;
        int off = j * 32 + (q ^ ((j >> 1) & 3)) * 8;
        Th[a] = *(const bf16x8*)&sThi[off];
        Tl[a] = *(const bf16x8*)&sTlo[off];
    }

    float* outbc = out + (size_t)bc * 65536;
    for (int it = 0; it < 16; ++it) {
        int i = it * 16 + m;
        // B-frags: Bu row i, chunk q, from LDS (swizzled slot)
        int boff = i * 32 + (q ^ ((i >> 1) & 3)) * 8;
        bf16x8 Bh = *(const bf16x8*)&sBhi[boff];
        bf16x8 Bl = *(const bf16x8*)&sBlo[boff];
        #pragma unroll
        for (int a = 0; a < 4; ++a) {
            f32x4 acc = {0.0f, 0.0f, 0.0f, 0.0f};
            acc = __builtin_amdgcn_mfma_f32_16x16x32_bf16(Tl[a], Bh, acc, 0, 0, 0);
            acc = __builtin_amdgcn_mfma_f32_16x16x32_bf16(Th[a], Bl, acc, 0, 0, 0);
            acc = __builtin_amdgcn_mfma_f32_16x16x32_bf16(Th[a], Bh, acc, 0, 0, 0);
            // D[row=q*4+r][col=m]: row -> j (consecutive in r), col -> i.
            float4 o4 = {acc[0], acc[1], acc[2], acc[3]};
            float* o = outbc + (size_t)i * 256 + (w * 4 + a) * 16 + q * 4;
            *(float4*)o = o4;   // 16B per lane; wave = 16 rows x 64B contiguous
        }
    }
}

extern "C" void kernel_launch(void* const* d_in, const int* in_sizes, int n_in,
                              void* d_out, int out_size, void* d_ws, size_t ws_size,
                              hipStream_t stream) {
    // d_in[0] = x (ignored), d_in[1] = K_mat (768*32*32 fp32)
    const float* K = (const float*)d_in[1];
    float* out = (float*)d_out;
    (void)d_ws; (void)ws_size;
    bez_fused_kernel<<<dim3(768), dim3(256), 0, stream>>>(K, out);
}